// Round 1
// baseline (441.228 us; speedup 1.0000x reference)
//
#include <hip/hip_runtime.h>
#include <math.h>

#define Bc 32
#define Rc 200
#define Nc 200
#define Dc 128
#define Hc 8
#define QKc 16
#define Kc 10
#define BRc (Bc*Rc)

// ---------------------------------------------------------------------------
// Kernel 1: kNN top-10 (exact JAX tie-break: lower index wins), gather,
// pad-with-mean, write bmat[BR,1280]; also writes cur_emb into qin[:,0:128].
// ---------------------------------------------------------------------------
__global__ __launch_bounds__(128) void knn_gather_kernel(
    const float* __restrict__ enc, const float* __restrict__ dist,
    const float* __restrict__ mask, const int* __restrict__ cur,
    float* __restrict__ bmat, float* __restrict__ qin)
{
    int br = blockIdx.x;
    int b = br / Rc;
    int t = threadIdx.x;
    __shared__ int s_idx[Kc];
    __shared__ float s_part[2][Kc];
    __shared__ float s_row[Kc];

    int c = cur[br];
    const float* drow = dist + ((size_t)b * Nc + c) * Nc;
    const float* mrow = mask + (size_t)br * Nc;

    if (t < 64) {  // wave 0 does the selection
        float v[4];
        #pragma unroll
        for (int j = 0; j < 4; ++j) {
            int n = t + 64 * j;
            float val = INFINITY;
            if (n < Nc) {
                float mv = mrow[n];
                if (!isinf(mv)) val = drow[n];   // mask is 0 or -inf
            }
            v[j] = val;
        }
        for (int k = 0; k < Kc; ++k) {
            float bv = v[0]; int bn = t;
            #pragma unroll
            for (int j = 1; j < 4; ++j) {
                if (v[j] < bv) { bv = v[j]; bn = t + 64 * j; }
            }
            #pragma unroll
            for (int off = 32; off > 0; off >>= 1) {
                float ov = __shfl_xor(bv, off);
                int   on = __shfl_xor(bn, off);
                if (ov < bv || (ov == bv && on < bn)) { bv = ov; bn = on; }
            }
            if (t == 0) s_idx[k] = isinf(bv) ? Nc : bn;
            int oj = bn >> 6, ol = bn & 63;
            if (t == ol) v[oj] = INFINITY;  // remove winner
        }
    }
    __syncthreads();

    // gather: thread t = column d
    float col[Kc]; float colsum = 0.f;
    #pragma unroll
    for (int k = 0; k < Kc; ++k) {
        int idx = s_idx[k];
        float val = 0.f;
        if (idx < Nc) val = enc[((size_t)b * Nc + idx) * Dc + t];
        col[k] = val; colsum += val;
    }
    int wave = t >> 6, lane = t & 63;
    #pragma unroll
    for (int k = 0; k < Kc; ++k) {
        float sv = col[k];
        #pragma unroll
        for (int off = 32; off > 0; off >>= 1) sv += __shfl_xor(sv, off);
        if (lane == 0) s_part[wave][k] = sv;
    }
    __syncthreads();
    if (t < Kc) s_row[t] = s_part[0][t] + s_part[1][t];
    __syncthreads();

    float cnt = 0.f;
    #pragma unroll
    for (int k = 0; k < Kc; ++k) cnt += (s_row[k] != 0.f) ? 1.f : 0.f;
    float mean = colsum / fmaxf(cnt, 1e-9f);

    float* brow = bmat + (size_t)br * (Kc * Dc);
    #pragma unroll
    for (int k = 0; k < Kc; ++k)
        brow[k * Dc + t] = (s_row[k] == 0.f) ? mean : col[k];

    // cur_emb -> qin[:, 0:128]
    qin[(size_t)br * 256 + t] = enc[((size_t)b * Nc + c) * Dc + t];
}

// ---------------------------------------------------------------------------
// Kernel 2: K/V projection. 8 node-rows per block for weight reuse.
// ---------------------------------------------------------------------------
__global__ __launch_bounds__(128) void kv_proj_kernel(
    const float* __restrict__ enc, const float* __restrict__ Wk,
    const float* __restrict__ Wv, float* __restrict__ kf, float* __restrict__ vf)
{
    __shared__ float se[8][Dc];
    int base = blockIdx.x * 8;
    int t = threadIdx.x;
    #pragma unroll
    for (int j = 0; j < 8; ++j) se[j][t] = enc[(size_t)(base + j) * Dc + t];
    __syncthreads();
    float ak[8] = {}, av[8] = {};
    for (int d = 0; d < Dc; ++d) {
        float wk = Wk[(size_t)d * 128 + t];
        float wv = Wv[(size_t)d * 128 + t];
        #pragma unroll
        for (int j = 0; j < 8; ++j) {
            ak[j] = fmaf(se[j][d], wk, ak[j]);
            av[j] = fmaf(se[j][d], wv, av[j]);
        }
    }
    #pragma unroll
    for (int j = 0; j < 8; ++j) {
        kf[(size_t)(base + j) * 128 + t] = ak[j];
        vf[(size_t)(base + j) * 128 + t] = av[j];
    }
}

// ---------------------------------------------------------------------------
// Kernel 3: generic fp32 tiled GEMM. C[m, coff+n] = (relu)(A@B + bias).
// BM=BN=64, BK=16, 256 threads, 4x4 per thread. All dims divide evenly.
// ---------------------------------------------------------------------------
template<bool RELU, bool HASBIAS>
__global__ __launch_bounds__(256) void gemm_kernel(
    const float* __restrict__ A, int lda,
    const float* __restrict__ Bw, int ldb,
    const float* __restrict__ bias,
    float* __restrict__ C, int ldc, int coff, int Kdim)
{
    __shared__ float As[16][68];   // A-tile transposed, stride 68 keeps 16B align
    __shared__ float Bs[16][64];
    int tid = threadIdx.x;
    int m0 = blockIdx.x * 64, n0 = blockIdx.y * 64;
    int tx = tid & 15, ty = tid >> 4;
    int am = tid >> 2, ak = (tid & 3) * 4;
    int bk = tid >> 4, bn = (tid & 15) * 4;
    float acc[4][4] = {};
    for (int k0 = 0; k0 < Kdim; k0 += 16) {
        float4 a  = *(const float4*)(A  + (size_t)(m0 + am) * lda + k0 + ak);
        float4 bv = *(const float4*)(Bw + (size_t)(k0 + bk) * ldb + n0 + bn);
        As[ak + 0][am] = a.x; As[ak + 1][am] = a.y;
        As[ak + 2][am] = a.z; As[ak + 3][am] = a.w;
        *(float4*)(&Bs[bk][bn]) = bv;
        __syncthreads();
        #pragma unroll
        for (int kk = 0; kk < 16; ++kk) {
            float4 av = *(const float4*)(&As[kk][ty * 4]);
            float4 bb = *(const float4*)(&Bs[kk][tx * 4]);
            float aa[4]  = {av.x, av.y, av.z, av.w};
            float bbv[4] = {bb.x, bb.y, bb.z, bb.w};
            #pragma unroll
            for (int i = 0; i < 4; ++i)
                #pragma unroll
                for (int j = 0; j < 4; ++j)
                    acc[i][j] = fmaf(aa[i], bbv[j], acc[i][j]);
        }
        __syncthreads();
    }
    #pragma unroll
    for (int i = 0; i < 4; ++i) {
        int m = m0 + ty * 4 + i;
        #pragma unroll
        for (int j = 0; j < 4; ++j) {
            int n = n0 + tx * 4 + j;
            float cval = acc[i][j];
            if (HASBIAS) cval += bias[n];
            if (RELU) cval = fmaxf(cval, 0.f);
            C[(size_t)m * ldc + coff + n] = cval;
        }
    }
}

// ---------------------------------------------------------------------------
// Kernel 4: attention per (b,h); K/V staged in LDS; one thread per query row
// with online softmax (guarded vs -inf - -inf = NaN).
// ---------------------------------------------------------------------------
__global__ __launch_bounds__(256) void attn_kernel(
    const float* __restrict__ q, const float* __restrict__ kf,
    const float* __restrict__ vf, const float* __restrict__ mask,
    float* __restrict__ att)
{
    int b = blockIdx.x / Hc, h = blockIdx.x % Hc;
    __shared__ float sk[Nc][QKc];
    __shared__ float sv[Nc][QKc];
    int t = threadIdx.x;
    for (int i = t; i < Nc * QKc; i += 256) {
        int n = i / QKc, j = i % QKc;
        sk[n][j] = kf[((size_t)b * Nc + n) * 128 + h * QKc + j];
        sv[n][j] = vf[((size_t)b * Nc + n) * 128 + h * QKc + j];
    }
    __syncthreads();
    int r = t;
    if (r < Rc) {
        float qreg[QKc];
        const float* qrow = q + ((size_t)b * Rc + r) * 128 + h * QKc;
        #pragma unroll
        for (int j = 0; j < QKc; ++j) qreg[j] = qrow[j];
        const float* mrow = mask + ((size_t)b * Rc + r) * Nc;
        float m = -INFINITY, l = 0.f, o[QKc] = {};
        for (int n = 0; n < Nc; ++n) {
            float s = 0.f;
            #pragma unroll
            for (int j = 0; j < QKc; ++j) s = fmaf(qreg[j], sk[n][j], s);
            s = s * 0.25f + mrow[n];       // 1/sqrt(16) = 0.25
            float mnew = fmaxf(m, s);
            float alpha, p;
            if (mnew == -INFINITY) { alpha = 1.f; p = 0.f; }
            else { alpha = expf(m - mnew); p = expf(s - mnew); }
            l = l * alpha + p;
            #pragma unroll
            for (int j = 0; j < QKc; ++j) o[j] = o[j] * alpha + p * sv[n][j];
            m = mnew;
        }
        float inv = 1.f / l;
        float* arow = att + ((size_t)b * Rc + r) * 128 + h * QKc;
        #pragma unroll
        for (int j = 0; j < QKc; ++j) arow[j] = o[j] * inv;
    }
}

// ---------------------------------------------------------------------------
// Kernel 5: logits = 10*tanh((mh @ enc^T)/sqrt(128)) + mask, into d_out.
// Tile: 64 r x 32 n per block, K=128 from LDS (both operands transposed).
// ---------------------------------------------------------------------------
__global__ __launch_bounds__(256) void final_logits_kernel(
    const float* __restrict__ mh, const float* __restrict__ enc,
    const float* __restrict__ mask, float* __restrict__ out)
{
    int b = blockIdx.x;
    int r0 = blockIdx.y * 64;
    int n0 = blockIdx.z * 32;
    __shared__ float smhT[Dc][68];
    __shared__ float senT[Dc][36];
    int t = threadIdx.x;
    for (int i = t; i < 64 * 32; i += 256) {
        int rr = i >> 5, dq = i & 31;
        int r = r0 + rr;
        float4 v = make_float4(0.f, 0.f, 0.f, 0.f);
        if (r < Rc) v = *(const float4*)(mh + ((size_t)b * Rc + r) * Dc + dq * 4);
        smhT[dq * 4 + 0][rr] = v.x; smhT[dq * 4 + 1][rr] = v.y;
        smhT[dq * 4 + 2][rr] = v.z; smhT[dq * 4 + 3][rr] = v.w;
    }
    for (int i = t; i < 32 * 32; i += 256) {
        int nn = i >> 5, dq = i & 31;
        int n = n0 + nn;
        float4 v = make_float4(0.f, 0.f, 0.f, 0.f);
        if (n < Nc) v = *(const float4*)(enc + ((size_t)b * Nc + n) * Dc + dq * 4);
        senT[dq * 4 + 0][nn] = v.x; senT[dq * 4 + 1][nn] = v.y;
        senT[dq * 4 + 2][nn] = v.z; senT[dq * 4 + 3][nn] = v.w;
    }
    __syncthreads();
    int tx = t & 7;    // 4 n each
    int ty = t >> 3;   // 2 r each
    float acc[2][4] = {};
    #pragma unroll 4
    for (int d = 0; d < Dc; ++d) {
        float2 a  = *(const float2*)(&smhT[d][ty * 2]);
        float4 bb = *(const float4*)(&senT[d][tx * 4]);
        acc[0][0] = fmaf(a.x, bb.x, acc[0][0]);
        acc[0][1] = fmaf(a.x, bb.y, acc[0][1]);
        acc[0][2] = fmaf(a.x, bb.z, acc[0][2]);
        acc[0][3] = fmaf(a.x, bb.w, acc[0][3]);
        acc[1][0] = fmaf(a.y, bb.x, acc[1][0]);
        acc[1][1] = fmaf(a.y, bb.y, acc[1][1]);
        acc[1][2] = fmaf(a.y, bb.z, acc[1][2]);
        acc[1][3] = fmaf(a.y, bb.w, acc[1][3]);
    }
    const float scale = 0.08838834764831843f;  // 1/sqrt(128)
    #pragma unroll
    for (int i = 0; i < 2; ++i) {
        int r = r0 + ty * 2 + i;
        #pragma unroll
        for (int j = 0; j < 4; ++j) {
            int n = n0 + tx * 4 + j;
            if (r < Rc && n < Nc) {
                float lg = 10.f * tanhf(acc[i][j] * scale)
                         + mask[((size_t)b * Rc + r) * Nc + n];
                out[((size_t)b * Rc + r) * Nc + n] = lg;
            }
        }
    }
}

// ---------------------------------------------------------------------------
// Kernel 6: row softmax over N=200, in place on d_out. One wave per row.
// ---------------------------------------------------------------------------
__global__ __launch_bounds__(64) void softmax_kernel(float* __restrict__ out)
{
    int br = blockIdx.x;
    float* row = out + (size_t)br * Nc;
    int t = threadIdx.x;
    float v[4]; float m = -INFINITY;
    #pragma unroll
    for (int j = 0; j < 4; ++j) {
        int n = t + 64 * j;
        v[j] = (n < Nc) ? row[n] : -INFINITY;
        m = fmaxf(m, v[j]);
    }
    #pragma unroll
    for (int off = 32; off > 0; off >>= 1) m = fmaxf(m, __shfl_xor(m, off));
    float e[4]; float s = 0.f;
    #pragma unroll
    for (int j = 0; j < 4; ++j) {
        e[j] = (v[j] == -INFINITY) ? 0.f : expf(v[j] - m);
        s += e[j];
    }
    #pragma unroll
    for (int off = 32; off > 0; off >>= 1) s += __shfl_xor(s, off);
    float inv = 1.f / s;
    #pragma unroll
    for (int j = 0; j < 4; ++j) {
        int n = t + 64 * j;
        if (n < Nc) row[n] = e[j] * inv;
    }
}

// ---------------------------------------------------------------------------
extern "C" void kernel_launch(void* const* d_in, const int* in_sizes, int n_in,
                              void* d_out, int out_size, void* d_ws, size_t ws_size,
                              hipStream_t stream)
{
    const float* enc  = (const float*)d_in[0];
    const float* dist = (const float*)d_in[1];
    const float* mask = (const float*)d_in[2];
    const int*   cur  = (const int*)d_in[3];
    const float* Wq   = (const float*)d_in[4];
    const float* Wk   = (const float*)d_in[5];
    const float* Wv   = (const float*)d_in[6];
    const float* Wmhc = (const float*)d_in[7];
    const float* bmhc = (const float*)d_in[8];
    const float* W1   = (const float*)d_in[9];
    const float* b1   = (const float*)d_in[10];
    const float* W2   = (const float*)d_in[11];
    const float* b2   = (const float*)d_in[12];
    float* out = (float*)d_out;

    float* ws   = (float*)d_ws;
    float* bmat = ws;                                  // BR x 1280
    float* h    = bmat + (size_t)BRc * 1280;           // BR x 640
    float* qin  = h    + (size_t)BRc * 640;            // BR x 256
    float* q    = qin  + (size_t)BRc * 256;            // BR x 128
    float* kf   = q    + (size_t)BRc * 128;            // B*N x 128
    float* vf   = kf   + (size_t)Bc * Nc * 128;        // B*N x 128
    float* att  = vf   + (size_t)Bc * Nc * 128;        // BR x 128
    float* mh   = att  + (size_t)BRc * 128;            // BR x 128

    knn_gather_kernel<<<BRc, 128, 0, stream>>>(enc, dist, mask, cur, bmat, qin);
    kv_proj_kernel<<<(Bc * Nc) / 8, 128, 0, stream>>>(enc, Wk, Wv, kf, vf);
    // h = relu(bmat @ W1 + b1)
    gemm_kernel<true,  true ><<<dim3(100, 10), 256, 0, stream>>>(bmat, 1280, W1, 640, b1, h, 640, 0, 1280);
    // qin[:,128:256] = h @ W2 + b2
    gemm_kernel<false, true ><<<dim3(100, 2), 256, 0, stream>>>(h, 640, W2, 128, b2, qin, 256, 128, 640);
    // q = qin @ Wq
    gemm_kernel<false, false><<<dim3(100, 2), 256, 0, stream>>>(qin, 256, Wq, 128, nullptr, q, 128, 0, 256);
    attn_kernel<<<Bc * Hc, 256, 0, stream>>>(q, kf, vf, mask, att);
    // mh = att @ Wmhc + b_mhc
    gemm_kernel<false, true ><<<dim3(100, 2), 256, 0, stream>>>(att, 128, Wmhc, 128, bmhc, mh, 128, 0, 128);
    final_logits_kernel<<<dim3(Bc, 4, 7), 256, 0, stream>>>(mh, enc, mask, out);
    softmax_kernel<<<BRc, 64, 0, stream>>>(out);
}

// Round 2
// 308.000 us; speedup vs baseline: 1.4326x; 1.4326x over previous
//
#include <hip/hip_runtime.h>
#include <hip/hip_bf16.h>
#include <math.h>

#define Bc 32
#define Rc 200
#define Nc 200
#define Dc 128
#define Hc 8
#define QKc 16
#define Kc 10
#define BRc (Bc*Rc)

typedef __attribute__((ext_vector_type(8))) short short8;
typedef __attribute__((ext_vector_type(4))) float f32x4;

#define GLOAD_LDS16(g, l) __builtin_amdgcn_global_load_lds( \
    (const __attribute__((address_space(1))) void*)(g), \
    (__attribute__((address_space(3))) void*)(l), 16, 0, 0)

// ---------------------------------------------------------------------------
// Kernel 0: fp32 W[Kd][Nd] -> bf16 Wt[Nd][Kd] (transpose + convert)
// ---------------------------------------------------------------------------
__global__ __launch_bounds__(256) void convert_transpose_kernel(
    const float* __restrict__ W, __hip_bfloat16* __restrict__ Wt, int Kd, int Nd)
{
    __shared__ float tile[32][33];
    int k0 = blockIdx.x * 32, n0 = blockIdx.y * 32;
    int tx = threadIdx.x & 31, ty = threadIdx.x >> 5;  // 32 x 8
    #pragma unroll
    for (int i = ty; i < 32; i += 8)
        tile[i][tx] = W[(size_t)(k0 + i) * Nd + n0 + tx];
    __syncthreads();
    #pragma unroll
    for (int i = ty; i < 32; i += 8)
        Wt[(size_t)(n0 + i) * Kd + k0 + tx] = __float2bfloat16(tile[tx][i]);
}

// ---------------------------------------------------------------------------
// Kernel 1: kNN top-10 (JAX tie-break: lower index wins), gather, pad-mean,
// write bmat[BR,1280] (bf16); cur_emb -> qin[:,0:128] (bf16).
// ---------------------------------------------------------------------------
__global__ __launch_bounds__(128) void knn_gather_kernel(
    const float* __restrict__ enc, const float* __restrict__ dist,
    const float* __restrict__ mask, const int* __restrict__ cur,
    __hip_bfloat16* __restrict__ bmat, __hip_bfloat16* __restrict__ qin)
{
    int br = blockIdx.x;
    int b = br / Rc;
    int t = threadIdx.x;
    __shared__ int s_idx[Kc];
    __shared__ float s_part[2][Kc];
    __shared__ float s_row[Kc];

    int c = cur[br];
    const float* drow = dist + ((size_t)b * Nc + c) * Nc;
    const float* mrow = mask + (size_t)br * Nc;

    if (t < 64) {
        float v[4];
        #pragma unroll
        for (int j = 0; j < 4; ++j) {
            int n = t + 64 * j;
            float val = INFINITY;
            if (n < Nc) {
                float mv = mrow[n];
                if (!isinf(mv)) val = drow[n];
            }
            v[j] = val;
        }
        for (int k = 0; k < Kc; ++k) {
            float bv = v[0]; int bn = t;
            #pragma unroll
            for (int j = 1; j < 4; ++j) {
                if (v[j] < bv) { bv = v[j]; bn = t + 64 * j; }
            }
            #pragma unroll
            for (int off = 32; off > 0; off >>= 1) {
                float ov = __shfl_xor(bv, off);
                int   on = __shfl_xor(bn, off);
                if (ov < bv || (ov == bv && on < bn)) { bv = ov; bn = on; }
            }
            if (t == 0) s_idx[k] = isinf(bv) ? Nc : bn;
            int oj = bn >> 6, ol = bn & 63;
            if (t == ol) v[oj] = INFINITY;
        }
    }
    __syncthreads();

    float col[Kc]; float colsum = 0.f;
    #pragma unroll
    for (int k = 0; k < Kc; ++k) {
        int idx = s_idx[k];
        float val = 0.f;
        if (idx < Nc) val = enc[((size_t)b * Nc + idx) * Dc + t];
        col[k] = val; colsum += val;
    }
    int wave = t >> 6, lane = t & 63;
    #pragma unroll
    for (int k = 0; k < Kc; ++k) {
        float sv = col[k];
        #pragma unroll
        for (int off = 32; off > 0; off >>= 1) sv += __shfl_xor(sv, off);
        if (lane == 0) s_part[wave][k] = sv;
    }
    __syncthreads();
    if (t < Kc) s_row[t] = s_part[0][t] + s_part[1][t];
    __syncthreads();

    float cnt = 0.f;
    #pragma unroll
    for (int k = 0; k < Kc; ++k) cnt += (s_row[k] != 0.f) ? 1.f : 0.f;
    float mean = colsum / fmaxf(cnt, 1e-9f);

    __hip_bfloat16* brow = bmat + (size_t)br * (Kc * Dc);
    #pragma unroll
    for (int k = 0; k < Kc; ++k)
        brow[k * Dc + t] = __float2bfloat16((s_row[k] == 0.f) ? mean : col[k]);

    qin[(size_t)br * 256 + t] = __float2bfloat16(enc[((size_t)b * Nc + c) * Dc + t]);
}

// ---------------------------------------------------------------------------
// Kernel 2: K/V projection (fp32). 8 node-rows per block.
// ---------------------------------------------------------------------------
__global__ __launch_bounds__(128) void kv_proj_kernel(
    const float* __restrict__ enc, const float* __restrict__ Wk,
    const float* __restrict__ Wv, float* __restrict__ kf, float* __restrict__ vf)
{
    __shared__ float se[8][Dc];
    int base = blockIdx.x * 8;
    int t = threadIdx.x;
    #pragma unroll
    for (int j = 0; j < 8; ++j) se[j][t] = enc[(size_t)(base + j) * Dc + t];
    __syncthreads();
    float ak[8] = {}, av[8] = {};
    for (int d = 0; d < Dc; ++d) {
        float wk = Wk[(size_t)d * 128 + t];
        float wv = Wv[(size_t)d * 128 + t];
        #pragma unroll
        for (int j = 0; j < 8; ++j) {
            ak[j] = fmaf(se[j][d], wk, ak[j]);
            av[j] = fmaf(se[j][d], wv, av[j]);
        }
    }
    #pragma unroll
    for (int j = 0; j < 8; ++j) {
        kf[(size_t)(base + j) * 128 + t] = ak[j];
        vf[(size_t)(base + j) * 128 + t] = av[j];
    }
}

// ---------------------------------------------------------------------------
// Kernel 3: bf16 MFMA GEMM. C = (relu)(A @ Bt^T + bias).
// A[M][Kdim] bf16 row-major, Bt[N][Kdim] bf16 (pre-transposed weights).
// 128x128 block tile, 4 waves x (64x64), 16x16x32 MFMA, global_load_lds w=16,
// column-group swizzle (cg' = (cg + (row>>1))&3) -> 2-way LDS conflicts (free).
// ---------------------------------------------------------------------------
template<bool RELU, bool HASBIAS, bool OUTBF16>
__global__ __launch_bounds__(256) void mfma_gemm_kernel(
    const __hip_bfloat16* __restrict__ A, int lda,
    const __hip_bfloat16* __restrict__ Bt, int Kdim,
    const float* __restrict__ bias,
    void* __restrict__ Cout, int ldc, int coff)
{
    __shared__ short Asl[128 * 32];
    __shared__ short Bsl[128 * 32];
    int tid = threadIdx.x;
    int wave = tid >> 6, lane = tid & 63;
    int m0 = blockIdx.x * 128, n0 = blockIdx.y * 128;

    // staging: wave stages rows [wave*32, wave*32+32) of both tiles, 2 chunks ea
    int lrow = lane >> 2;            // row within 16-row chunk
    int cg   = lane & 3;             // LDS column-group slot this lane fills
    int ss   = (lane >> 3) & 3;      // store-side swizzle = (tile_row>>1)&3
    int gq   = (cg - ss) & 3;        // global column-group to fetch
    const short* Ab = (const short*)A;
    const short* Bb = (const short*)Bt;
    const short* gA0 = Ab + (size_t)(m0 + wave * 32 + lrow) * lda + gq * 8;
    const short* gA1 = gA0 + (size_t)16 * lda;
    const short* gB0 = Bb + (size_t)(n0 + wave * 32 + lrow) * Kdim + gq * 8;
    const short* gB1 = gB0 + (size_t)16 * Kdim;
    short* lA0 = &Asl[(wave * 32) * 32];
    short* lA1 = &Asl[(wave * 32 + 16) * 32];
    short* lB0 = &Bsl[(wave * 32) * 32];
    short* lB1 = &Bsl[(wave * 32 + 16) * 32];

    // compute mapping: wave (wm,wn) covers 64x64
    int wm = wave >> 1, wn = wave & 1;
    int rrow = lane & 15, quad = lane >> 4;
    int srd  = (rrow >> 1) & 3;      // read-side swizzle (tile-base mult of 16)

    f32x4 acc[4][4];
    #pragma unroll
    for (int i = 0; i < 4; ++i)
        #pragma unroll
        for (int j = 0; j < 4; ++j)
            acc[i][j] = (f32x4){0.f, 0.f, 0.f, 0.f};

    for (int k0 = 0; k0 < Kdim; k0 += 32) {
        __syncthreads();
        GLOAD_LDS16(gA0 + k0, lA0);
        GLOAD_LDS16(gA1 + k0, lA1);
        GLOAD_LDS16(gB0 + k0, lB0);
        GLOAD_LDS16(gB1 + k0, lB1);
        __syncthreads();
        short8 afr[4], bfr[4];
        #pragma unroll
        for (int mt = 0; mt < 4; ++mt) {
            int rowa = wm * 64 + mt * 16 + rrow;
            afr[mt] = *(const short8*)&Asl[rowa * 32 + ((quad + srd) & 3) * 8];
            int rowb = wn * 64 + mt * 16 + rrow;
            bfr[mt] = *(const short8*)&Bsl[rowb * 32 + ((quad + srd) & 3) * 8];
        }
        #pragma unroll
        for (int mt = 0; mt < 4; ++mt)
            #pragma unroll
            for (int nt = 0; nt < 4; ++nt)
                acc[mt][nt] = __builtin_amdgcn_mfma_f32_16x16x32_bf16(
                    afr[mt], bfr[nt], acc[mt][nt], 0, 0, 0);
    }

    // epilogue: C/D layout col=lane&15, row=quad*4+i
    #pragma unroll
    for (int mt = 0; mt < 4; ++mt) {
        #pragma unroll
        for (int nt = 0; nt < 4; ++nt) {
            int n = wn * 64 + nt * 16 + rrow;       // within [0,N)
            float bv = HASBIAS ? bias[n0 + n] : 0.f;
            #pragma unroll
            for (int i = 0; i < 4; ++i) {
                int m = m0 + wm * 64 + mt * 16 + quad * 4 + i;
                float v = acc[mt][nt][i] + bv;
                if (RELU) v = fmaxf(v, 0.f);
                size_t off = (size_t)m * ldc + coff + n0 + n;
                if (OUTBF16) ((__hip_bfloat16*)Cout)[off] = __float2bfloat16(v);
                else         ((float*)Cout)[off] = v;
            }
        }
    }
}

// ---------------------------------------------------------------------------
// Kernel 4: attention per (b,h); K/V in LDS; one thread per query row,
// online softmax; att written bf16.
// ---------------------------------------------------------------------------
__global__ __launch_bounds__(256) void attn_kernel(
    const float* __restrict__ q, const float* __restrict__ kf,
    const float* __restrict__ vf, const float* __restrict__ mask,
    __hip_bfloat16* __restrict__ att)
{
    int b = blockIdx.x / Hc, h = blockIdx.x % Hc;
    __shared__ float sk[Nc][QKc];
    __shared__ float sv[Nc][QKc];
    int t = threadIdx.x;
    for (int i = t; i < Nc * QKc; i += 256) {
        int n = i / QKc, j = i % QKc;
        sk[n][j] = kf[((size_t)b * Nc + n) * 128 + h * QKc + j];
        sv[n][j] = vf[((size_t)b * Nc + n) * 128 + h * QKc + j];
    }
    __syncthreads();
    int r = t;
    if (r < Rc) {
        float qreg[QKc];
        const float* qrow = q + ((size_t)b * Rc + r) * 128 + h * QKc;
        #pragma unroll
        for (int j = 0; j < QKc; ++j) qreg[j] = qrow[j];
        const float* mrow = mask + ((size_t)b * Rc + r) * Nc;
        float m = -INFINITY, l = 0.f, o[QKc] = {};
        for (int n = 0; n < Nc; ++n) {
            float s = 0.f;
            #pragma unroll
            for (int j = 0; j < QKc; ++j) s = fmaf(qreg[j], sk[n][j], s);
            s = s * 0.25f + mrow[n];
            float mnew = fmaxf(m, s);
            float alpha, p;
            if (mnew == -INFINITY) { alpha = 1.f; p = 0.f; }
            else { alpha = expf(m - mnew); p = expf(s - mnew); }
            l = l * alpha + p;
            #pragma unroll
            for (int j = 0; j < QKc; ++j) o[j] = o[j] * alpha + p * sv[n][j];
            m = mnew;
        }
        float inv = 1.f / l;
        __hip_bfloat16* arow = att + ((size_t)b * Rc + r) * 128 + h * QKc;
        #pragma unroll
        for (int j = 0; j < QKc; ++j) arow[j] = __float2bfloat16(o[j] * inv);
    }
}

// ---------------------------------------------------------------------------
// Kernel 5: logits = 10*tanh((mh @ enc^T)/sqrt(128)) + mask -> d_out.
// ---------------------------------------------------------------------------
__global__ __launch_bounds__(256) void final_logits_kernel(
    const float* __restrict__ mh, const float* __restrict__ enc,
    const float* __restrict__ mask, float* __restrict__ out)
{
    int b = blockIdx.x;
    int r0 = blockIdx.y * 64;
    int n0 = blockIdx.z * 32;
    __shared__ float smhT[Dc][68];
    __shared__ float senT[Dc][36];
    int t = threadIdx.x;
    for (int i = t; i < 64 * 32; i += 256) {
        int rr = i >> 5, dq = i & 31;
        int r = r0 + rr;
        float4 v = make_float4(0.f, 0.f, 0.f, 0.f);
        if (r < Rc) v = *(const float4*)(mh + ((size_t)b * Rc + r) * Dc + dq * 4);
        smhT[dq * 4 + 0][rr] = v.x; smhT[dq * 4 + 1][rr] = v.y;
        smhT[dq * 4 + 2][rr] = v.z; smhT[dq * 4 + 3][rr] = v.w;
    }
    for (int i = t; i < 32 * 32; i += 256) {
        int nn = i >> 5, dq = i & 31;
        int n = n0 + nn;
        float4 v = make_float4(0.f, 0.f, 0.f, 0.f);
        if (n < Nc) v = *(const float4*)(enc + ((size_t)b * Nc + n) * Dc + dq * 4);
        senT[dq * 4 + 0][nn] = v.x; senT[dq * 4 + 1][nn] = v.y;
        senT[dq * 4 + 2][nn] = v.z; senT[dq * 4 + 3][nn] = v.w;
    }
    __syncthreads();
    int tx = t & 7;
    int ty = t >> 3;
    float acc[2][4] = {};
    #pragma unroll 4
    for (int d = 0; d < Dc; ++d) {
        float2 a  = *(const float2*)(&smhT[d][ty * 2]);
        float4 bb = *(const float4*)(&senT[d][tx * 4]);
        acc[0][0] = fmaf(a.x, bb.x, acc[0][0]);
        acc[0][1] = fmaf(a.x, bb.y, acc[0][1]);
        acc[0][2] = fmaf(a.x, bb.z, acc[0][2]);
        acc[0][3] = fmaf(a.x, bb.w, acc[0][3]);
        acc[1][0] = fmaf(a.y, bb.x, acc[1][0]);
        acc[1][1] = fmaf(a.y, bb.y, acc[1][1]);
        acc[1][2] = fmaf(a.y, bb.z, acc[1][2]);
        acc[1][3] = fmaf(a.y, bb.w, acc[1][3]);
    }
    const float scale = 0.08838834764831843f;
    #pragma unroll
    for (int i = 0; i < 2; ++i) {
        int r = r0 + ty * 2 + i;
        #pragma unroll
        for (int j = 0; j < 4; ++j) {
            int n = n0 + tx * 4 + j;
            if (r < Rc && n < Nc) {
                float lg = 10.f * tanhf(acc[i][j] * scale)
                         + mask[((size_t)b * Rc + r) * Nc + n];
                out[((size_t)b * Rc + r) * Nc + n] = lg;
            }
        }
    }
}

// ---------------------------------------------------------------------------
// Kernel 6: row softmax over N=200, in place.
// ---------------------------------------------------------------------------
__global__ __launch_bounds__(64) void softmax_kernel(float* __restrict__ out)
{
    int br = blockIdx.x;
    float* row = out + (size_t)br * Nc;
    int t = threadIdx.x;
    float v[4]; float m = -INFINITY;
    #pragma unroll
    for (int j = 0; j < 4; ++j) {
        int n = t + 64 * j;
        v[j] = (n < Nc) ? row[n] : -INFINITY;
        m = fmaxf(m, v[j]);
    }
    #pragma unroll
    for (int off = 32; off > 0; off >>= 1) m = fmaxf(m, __shfl_xor(m, off));
    float e[4]; float s = 0.f;
    #pragma unroll
    for (int j = 0; j < 4; ++j) {
        e[j] = (v[j] == -INFINITY) ? 0.f : expf(v[j] - m);
        s += e[j];
    }
    #pragma unroll
    for (int off = 32; off > 0; off >>= 1) s += __shfl_xor(s, off);
    float inv = 1.f / s;
    #pragma unroll
    for (int j = 0; j < 4; ++j) {
        int n = t + 64 * j;
        if (n < Nc) row[n] = e[j] * inv;
    }
}

// ---------------------------------------------------------------------------
extern "C" void kernel_launch(void* const* d_in, const int* in_sizes, int n_in,
                              void* d_out, int out_size, void* d_ws, size_t ws_size,
                              hipStream_t stream)
{
    const float* enc  = (const float*)d_in[0];
    const float* dist = (const float*)d_in[1];
    const float* mask = (const float*)d_in[2];
    const int*   cur  = (const int*)d_in[3];
    const float* Wq   = (const float*)d_in[4];
    const float* Wk   = (const float*)d_in[5];
    const float* Wv   = (const float*)d_in[6];
    const float* Wmhc = (const float*)d_in[7];
    const float* bmhc = (const float*)d_in[8];
    const float* W1   = (const float*)d_in[9];
    const float* b1   = (const float*)d_in[10];
    const float* W2   = (const float*)d_in[11];
    const float* b2   = (const float*)d_in[12];
    float* out = (float*)d_out;

    // workspace layout (bytes, 256-aligned)
    char* ws = (char*)d_ws;
    size_t off = 0;
    auto alloc = [&](size_t bytes) { char* p = ws + off; off += (bytes + 255) & ~(size_t)255; return p; };
    __hip_bfloat16* W1t  = (__hip_bfloat16*)alloc((size_t)640 * 1280 * 2);
    __hip_bfloat16* W2t  = (__hip_bfloat16*)alloc((size_t)128 * 640 * 2);
    __hip_bfloat16* Wqt  = (__hip_bfloat16*)alloc((size_t)128 * 256 * 2);
    __hip_bfloat16* Wmt  = (__hip_bfloat16*)alloc((size_t)128 * 128 * 2);
    __hip_bfloat16* bmat = (__hip_bfloat16*)alloc((size_t)BRc * 1280 * 2);
    __hip_bfloat16* h    = (__hip_bfloat16*)alloc((size_t)BRc * 640 * 2);
    __hip_bfloat16* qin  = (__hip_bfloat16*)alloc((size_t)BRc * 256 * 2);
    float* q   = (float*)alloc((size_t)BRc * 128 * 4);
    float* kf  = (float*)alloc((size_t)Bc * Nc * 128 * 4);
    float* vf  = (float*)alloc((size_t)Bc * Nc * 128 * 4);
    __hip_bfloat16* att = (__hip_bfloat16*)alloc((size_t)BRc * 128 * 2);
    float* mh  = (float*)alloc((size_t)BRc * 128 * 4);

    // weight transpose+convert: W[K][N] -> Wt[N][K] bf16
    convert_transpose_kernel<<<dim3(1280 / 32, 640 / 32), 256, 0, stream>>>(W1, W1t, 1280, 640);
    convert_transpose_kernel<<<dim3(640 / 32, 128 / 32), 256, 0, stream>>>(W2, W2t, 640, 128);
    convert_transpose_kernel<<<dim3(256 / 32, 128 / 32), 256, 0, stream>>>(Wq, Wqt, 256, 128);
    convert_transpose_kernel<<<dim3(128 / 32, 128 / 32), 256, 0, stream>>>(Wmhc, Wmt, 128, 128);

    knn_gather_kernel<<<BRc, 128, 0, stream>>>(enc, dist, mask, cur, bmat, qin);
    kv_proj_kernel<<<(Bc * Nc) / 8, 128, 0, stream>>>(enc, Wk, Wv, kf, vf);

    // h = relu(bmat @ W1 + b1)     [6400,1280]x[1280,640] -> bf16
    mfma_gemm_kernel<true, true, true><<<dim3(BRc / 128, 640 / 128), 256, 0, stream>>>(
        bmat, 1280, W1t, 1280, b1, h, 640, 0);
    // qin[:,128:256] = h @ W2 + b2 [6400,640]x[640,128] -> bf16
    mfma_gemm_kernel<false, true, true><<<dim3(BRc / 128, 1), 256, 0, stream>>>(
        h, 640, W2t, 640, b2, qin, 256, 128);
    // q = qin @ Wq                 [6400,256]x[256,128] -> fp32
    mfma_gemm_kernel<false, false, false><<<dim3(BRc / 128, 1), 256, 0, stream>>>(
        qin, 256, Wqt, 256, nullptr, q, 128, 0);

    attn_kernel<<<Bc * Hc, 256, 0, stream>>>(q, kf, vf, mask, att);

    // mh = att @ Wmhc + b_mhc      [6400,128]x[128,128] -> fp32
    mfma_gemm_kernel<false, true, false><<<dim3(BRc / 128, 1), 256, 0, stream>>>(
        att, 128, Wmt, 128, bmhc, mh, 128, 0);

    final_logits_kernel<<<dim3(Bc, 4, 7), 256, 0, stream>>>(mh, enc, mask, out);
    softmax_kernel<<<BRc, 64, 0, stream>>>(out);
}

// Round 3
// 274.862 us; speedup vs baseline: 1.6053x; 1.1206x over previous
//
#include <hip/hip_runtime.h>
#include <hip/hip_bf16.h>
#include <math.h>

#define Bc 32
#define Rc 200
#define Nc 200
#define Dc 128
#define Hc 8
#define QKc 16
#define Kc 10
#define BRc (Bc*Rc)

typedef __attribute__((ext_vector_type(8))) short short8;
typedef __attribute__((ext_vector_type(4))) float f32x4;

#define GLOAD_LDS16(g, l) __builtin_amdgcn_global_load_lds( \
    (const __attribute__((address_space(1))) void*)(g), \
    (__attribute__((address_space(3))) void*)(l), 16, 0, 0)

// ---------------------------------------------------------------------------
// Kernel 0a: fp32 W[Kd][Nd] -> bf16 Wt[Nd][Kd] (transpose + convert)
// ---------------------------------------------------------------------------
__global__ __launch_bounds__(256) void convert_transpose_kernel(
    const float* __restrict__ W, __hip_bfloat16* __restrict__ Wt, int Kd, int Nd)
{
    __shared__ float tile[32][33];
    int k0 = blockIdx.x * 32, n0 = blockIdx.y * 32;
    int tx = threadIdx.x & 31, ty = threadIdx.x >> 5;  // 32 x 8
    #pragma unroll
    for (int i = ty; i < 32; i += 8)
        tile[i][tx] = W[(size_t)(k0 + i) * Nd + n0 + tx];
    __syncthreads();
    #pragma unroll
    for (int i = ty; i < 32; i += 8)
        Wt[(size_t)(n0 + i) * Kd + k0 + tx] = __float2bfloat16(tile[tx][i]);
}

// ---------------------------------------------------------------------------
// Kernel 0b: fp32 -> bf16 flat convert (n divisible by 4)
// ---------------------------------------------------------------------------
__global__ __launch_bounds__(256) void f32_to_bf16_kernel(
    const float* __restrict__ in, __hip_bfloat16* __restrict__ out, int n)
{
    int i = (blockIdx.x * 256 + threadIdx.x) * 4;
    if (i < n) {
        float4 v = *(const float4*)(in + i);
        out[i + 0] = __float2bfloat16(v.x);
        out[i + 1] = __float2bfloat16(v.y);
        out[i + 2] = __float2bfloat16(v.z);
        out[i + 3] = __float2bfloat16(v.w);
    }
}

// ---------------------------------------------------------------------------
// Kernel 1: kNN top-10 (JAX tie-break: lower index wins), gather, pad-mean,
// write bmat[BR,1280] (bf16); cur_emb -> qin[:,0:128] (bf16).
// ---------------------------------------------------------------------------
__global__ __launch_bounds__(128) void knn_gather_kernel(
    const float* __restrict__ enc, const float* __restrict__ dist,
    const float* __restrict__ mask, const int* __restrict__ cur,
    __hip_bfloat16* __restrict__ bmat, __hip_bfloat16* __restrict__ qin)
{
    int br = blockIdx.x;
    int b = br / Rc;
    int t = threadIdx.x;
    __shared__ int s_idx[Kc];
    __shared__ float s_part[2][Kc];
    __shared__ float s_row[Kc];

    int c = cur[br];
    const float* drow = dist + ((size_t)b * Nc + c) * Nc;
    const float* mrow = mask + (size_t)br * Nc;

    if (t < 64) {
        float v[4];
        #pragma unroll
        for (int j = 0; j < 4; ++j) {
            int n = t + 64 * j;
            float val = INFINITY;
            if (n < Nc) {
                float mv = mrow[n];
                if (!isinf(mv)) val = drow[n];
            }
            v[j] = val;
        }
        for (int k = 0; k < Kc; ++k) {
            float bv = v[0]; int bn = t;
            #pragma unroll
            for (int j = 1; j < 4; ++j) {
                if (v[j] < bv) { bv = v[j]; bn = t + 64 * j; }
            }
            #pragma unroll
            for (int off = 32; off > 0; off >>= 1) {
                float ov = __shfl_xor(bv, off);
                int   on = __shfl_xor(bn, off);
                if (ov < bv || (ov == bv && on < bn)) { bv = ov; bn = on; }
            }
            if (t == 0) s_idx[k] = isinf(bv) ? Nc : bn;
            int oj = bn >> 6, ol = bn & 63;
            if (t == ol) v[oj] = INFINITY;
        }
    }
    __syncthreads();

    float col[Kc]; float colsum = 0.f;
    #pragma unroll
    for (int k = 0; k < Kc; ++k) {
        int idx = s_idx[k];
        float val = 0.f;
        if (idx < Nc) val = enc[((size_t)b * Nc + idx) * Dc + t];
        col[k] = val; colsum += val;
    }
    int wave = t >> 6, lane = t & 63;
    #pragma unroll
    for (int k = 0; k < Kc; ++k) {
        float sv = col[k];
        #pragma unroll
        for (int off = 32; off > 0; off >>= 1) sv += __shfl_xor(sv, off);
        if (lane == 0) s_part[wave][k] = sv;
    }
    __syncthreads();
    if (t < Kc) s_row[t] = s_part[0][t] + s_part[1][t];
    __syncthreads();

    float cnt = 0.f;
    #pragma unroll
    for (int k = 0; k < Kc; ++k) cnt += (s_row[k] != 0.f) ? 1.f : 0.f;
    float mean = colsum / fmaxf(cnt, 1e-9f);

    __hip_bfloat16* brow = bmat + (size_t)br * (Kc * Dc);
    #pragma unroll
    for (int k = 0; k < Kc; ++k)
        brow[k * Dc + t] = __float2bfloat16((s_row[k] == 0.f) ? mean : col[k]);

    qin[(size_t)br * 256 + t] = __float2bfloat16(enc[((size_t)b * Nc + c) * Dc + t]);
}

// ---------------------------------------------------------------------------
// Kernel 3: bf16 MFMA GEMM. C = (relu)(A @ Bt^T + bias).
// A[M][Kdim] bf16 row-major, Bt[N][Kdim] bf16 (pre-transposed weights).
// 128x128 block tile, 4 waves x (64x64), 16x16x32 MFMA, global_load_lds w=16,
// column-group swizzle -> 2-way LDS conflicts (free).
// ---------------------------------------------------------------------------
template<bool RELU, bool HASBIAS, bool OUTBF16>
__global__ __launch_bounds__(256) void mfma_gemm_kernel(
    const __hip_bfloat16* __restrict__ A, int lda,
    const __hip_bfloat16* __restrict__ Bt, int Kdim,
    const float* __restrict__ bias,
    void* __restrict__ Cout, int ldc, int coff)
{
    __shared__ short Asl[128 * 32];
    __shared__ short Bsl[128 * 32];
    int tid = threadIdx.x;
    int wave = tid >> 6, lane = tid & 63;
    int m0 = blockIdx.x * 128, n0 = blockIdx.y * 128;

    int lrow = lane >> 2;
    int cg   = lane & 3;
    int ss   = (lane >> 3) & 3;
    int gq   = (cg - ss) & 3;
    const short* Ab = (const short*)A;
    const short* Bb = (const short*)Bt;
    const short* gA0 = Ab + (size_t)(m0 + wave * 32 + lrow) * lda + gq * 8;
    const short* gA1 = gA0 + (size_t)16 * lda;
    const short* gB0 = Bb + (size_t)(n0 + wave * 32 + lrow) * Kdim + gq * 8;
    const short* gB1 = gB0 + (size_t)16 * Kdim;
    short* lA0 = &Asl[(wave * 32) * 32];
    short* lA1 = &Asl[(wave * 32 + 16) * 32];
    short* lB0 = &Bsl[(wave * 32) * 32];
    short* lB1 = &Bsl[(wave * 32 + 16) * 32];

    int wm = wave >> 1, wn = wave & 1;
    int rrow = lane & 15, quad = lane >> 4;
    int srd  = (rrow >> 1) & 3;

    f32x4 acc[4][4];
    #pragma unroll
    for (int i = 0; i < 4; ++i)
        #pragma unroll
        for (int j = 0; j < 4; ++j)
            acc[i][j] = (f32x4){0.f, 0.f, 0.f, 0.f};

    for (int k0 = 0; k0 < Kdim; k0 += 32) {
        __syncthreads();
        GLOAD_LDS16(gA0 + k0, lA0);
        GLOAD_LDS16(gA1 + k0, lA1);
        GLOAD_LDS16(gB0 + k0, lB0);
        GLOAD_LDS16(gB1 + k0, lB1);
        __syncthreads();
        short8 afr[4], bfr[4];
        #pragma unroll
        for (int mt = 0; mt < 4; ++mt) {
            int rowa = wm * 64 + mt * 16 + rrow;
            afr[mt] = *(const short8*)&Asl[rowa * 32 + ((quad + srd) & 3) * 8];
            int rowb = wn * 64 + mt * 16 + rrow;
            bfr[mt] = *(const short8*)&Bsl[rowb * 32 + ((quad + srd) & 3) * 8];
        }
        #pragma unroll
        for (int mt = 0; mt < 4; ++mt)
            #pragma unroll
            for (int nt = 0; nt < 4; ++nt)
                acc[mt][nt] = __builtin_amdgcn_mfma_f32_16x16x32_bf16(
                    afr[mt], bfr[nt], acc[mt][nt], 0, 0, 0);
    }

    #pragma unroll
    for (int mt = 0; mt < 4; ++mt) {
        #pragma unroll
        for (int nt = 0; nt < 4; ++nt) {
            int n = wn * 64 + nt * 16 + rrow;
            float bv = HASBIAS ? bias[n0 + n] : 0.f;
            #pragma unroll
            for (int i = 0; i < 4; ++i) {
                int m = m0 + wm * 64 + mt * 16 + quad * 4 + i;
                float v = acc[mt][nt][i] + bv;
                if (RELU) v = fmaxf(v, 0.f);
                size_t off = (size_t)m * ldc + coff + n0 + n;
                if (OUTBF16) ((__hip_bfloat16*)Cout)[off] = __float2bfloat16(v);
                else         ((float*)Cout)[off] = v;
            }
        }
    }
}

// ---------------------------------------------------------------------------
// Kernel 4: attention per (b,h). 4 threads per query row, each owns a 50-wide
// n-chunk with local online softmax; 4-lane shuffle merge. K/V bf16 in global,
// fp32 float4 rows in LDS (row stride 5 float4s kills the 4-way bank alias).
// ---------------------------------------------------------------------------
__global__ __launch_bounds__(832) void attn_kernel(
    const float* __restrict__ q, const __hip_bfloat16* __restrict__ kf,
    const __hip_bfloat16* __restrict__ vf, const float* __restrict__ mask,
    __hip_bfloat16* __restrict__ att)
{
    int b = blockIdx.x / Hc, h = blockIdx.x % Hc;
    __shared__ float4 sk[Nc][5];
    __shared__ float4 sv[Nc][5];
    int t = threadIdx.x;

    for (int i = t; i < Nc * 4; i += 832) {
        int n = i >> 2, g = i & 3;
        const __hip_bfloat16* kr = kf + ((size_t)b * Nc + n) * 128 + h * QKc + g * 4;
        const __hip_bfloat16* vr = vf + ((size_t)b * Nc + n) * 128 + h * QKc + g * 4;
        sk[n][g] = make_float4(__bfloat162float(kr[0]), __bfloat162float(kr[1]),
                               __bfloat162float(kr[2]), __bfloat162float(kr[3]));
        sv[n][g] = make_float4(__bfloat162float(vr[0]), __bfloat162float(vr[1]),
                               __bfloat162float(vr[2]), __bfloat162float(vr[3]));
    }
    __syncthreads();

    int r = t >> 2, c = t & 3;
    if (r < Rc) {
        float4 q0, q1, q2, q3;
        {
            const float* qrow = q + ((size_t)b * Rc + r) * 128 + h * QKc;
            q0 = *(const float4*)(qrow + 0);
            q1 = *(const float4*)(qrow + 4);
            q2 = *(const float4*)(qrow + 8);
            q3 = *(const float4*)(qrow + 12);
        }
        const float* mrow = mask + ((size_t)b * Rc + r) * Nc;
        float m = -INFINITY, l = 0.f, o[QKc] = {};
        int n1 = c * 50 + 50;
        for (int n = c * 50; n < n1; ++n) {
            float4 k0 = sk[n][0], k1 = sk[n][1], k2 = sk[n][2], k3 = sk[n][3];
            float s = q0.x * k0.x + q0.y * k0.y + q0.z * k0.z + q0.w * k0.w
                    + q1.x * k1.x + q1.y * k1.y + q1.z * k1.z + q1.w * k1.w
                    + q2.x * k2.x + q2.y * k2.y + q2.z * k2.z + q2.w * k2.w
                    + q3.x * k3.x + q3.y * k3.y + q3.z * k3.z + q3.w * k3.w;
            s = s * 0.25f + mrow[n];
            float mnew = fmaxf(m, s);
            float alpha, p;
            if (mnew == -INFINITY) { alpha = 1.f; p = 0.f; }
            else { alpha = expf(m - mnew); p = expf(s - mnew); }
            l = l * alpha + p;
            float4 v0 = sv[n][0], v1 = sv[n][1], v2 = sv[n][2], v3 = sv[n][3];
            o[0]  = o[0]  * alpha + p * v0.x;  o[1]  = o[1]  * alpha + p * v0.y;
            o[2]  = o[2]  * alpha + p * v0.z;  o[3]  = o[3]  * alpha + p * v0.w;
            o[4]  = o[4]  * alpha + p * v1.x;  o[5]  = o[5]  * alpha + p * v1.y;
            o[6]  = o[6]  * alpha + p * v1.z;  o[7]  = o[7]  * alpha + p * v1.w;
            o[8]  = o[8]  * alpha + p * v2.x;  o[9]  = o[9]  * alpha + p * v2.y;
            o[10] = o[10] * alpha + p * v2.z;  o[11] = o[11] * alpha + p * v2.w;
            o[12] = o[12] * alpha + p * v3.x;  o[13] = o[13] * alpha + p * v3.y;
            o[14] = o[14] * alpha + p * v3.z;  o[15] = o[15] * alpha + p * v3.w;
            m = mnew;
        }
        // merge the 4 chunk-partials (lanes c=0..3 of each 4-lane group)
        float M = m;
        M = fmaxf(M, __shfl_xor(M, 1));
        M = fmaxf(M, __shfl_xor(M, 2));
        float sc = (m == -INFINITY) ? 0.f : expf(m - M);
        l *= sc;
        l += __shfl_xor(l, 1);
        l += __shfl_xor(l, 2);
        #pragma unroll
        for (int j = 0; j < QKc; ++j) {
            float oj = o[j] * sc;
            oj += __shfl_xor(oj, 1);
            oj += __shfl_xor(oj, 2);
            o[j] = oj;
        }
        if (c == 0) {
            float inv = (l > 0.f) ? 1.f / l : 0.f;
            __hip_bfloat16* arow = att + ((size_t)b * Rc + r) * 128 + h * QKc;
            #pragma unroll
            for (int j = 0; j < QKc; ++j) arow[j] = __float2bfloat16(o[j] * inv);
        }
    }
}

// ---------------------------------------------------------------------------
// Kernel 5: logits = 10*tanh((mh @ enc^T)/sqrt(128)) + mask -> d_out.
// ---------------------------------------------------------------------------
__global__ __launch_bounds__(256) void final_logits_kernel(
    const float* __restrict__ mh, const float* __restrict__ enc,
    const float* __restrict__ mask, float* __restrict__ out)
{
    int b = blockIdx.x;
    int r0 = blockIdx.y * 64;
    int n0 = blockIdx.z * 32;
    __shared__ float smhT[Dc][68];
    __shared__ float senT[Dc][36];
    int t = threadIdx.x;
    for (int i = t; i < 64 * 32; i += 256) {
        int rr = i >> 5, dq = i & 31;
        int r = r0 + rr;
        float4 v = make_float4(0.f, 0.f, 0.f, 0.f);
        if (r < Rc) v = *(const float4*)(mh + ((size_t)b * Rc + r) * Dc + dq * 4);
        smhT[dq * 4 + 0][rr] = v.x; smhT[dq * 4 + 1][rr] = v.y;
        smhT[dq * 4 + 2][rr] = v.z; smhT[dq * 4 + 3][rr] = v.w;
    }
    for (int i = t; i < 32 * 32; i += 256) {
        int nn = i >> 5, dq = i & 31;
        int n = n0 + nn;
        float4 v = make_float4(0.f, 0.f, 0.f, 0.f);
        if (n < Nc) v = *(const float4*)(enc + ((size_t)b * Nc + n) * Dc + dq * 4);
        senT[dq * 4 + 0][nn] = v.x; senT[dq * 4 + 1][nn] = v.y;
        senT[dq * 4 + 2][nn] = v.z; senT[dq * 4 + 3][nn] = v.w;
    }
    __syncthreads();
    int tx = t & 7;
    int ty = t >> 3;
    float acc[2][4] = {};
    #pragma unroll 4
    for (int d = 0; d < Dc; ++d) {
        float2 a  = *(const float2*)(&smhT[d][ty * 2]);
        float4 bb = *(const float4*)(&senT[d][tx * 4]);
        acc[0][0] = fmaf(a.x, bb.x, acc[0][0]);
        acc[0][1] = fmaf(a.x, bb.y, acc[0][1]);
        acc[0][2] = fmaf(a.x, bb.z, acc[0][2]);
        acc[0][3] = fmaf(a.x, bb.w, acc[0][3]);
        acc[1][0] = fmaf(a.y, bb.x, acc[1][0]);
        acc[1][1] = fmaf(a.y, bb.y, acc[1][1]);
        acc[1][2] = fmaf(a.y, bb.z, acc[1][2]);
        acc[1][3] = fmaf(a.y, bb.w, acc[1][3]);
    }
    const float scale = 0.08838834764831843f;
    #pragma unroll
    for (int i = 0; i < 2; ++i) {
        int r = r0 + ty * 2 + i;
        #pragma unroll
        for (int j = 0; j < 4; ++j) {
            int n = n0 + tx * 4 + j;
            if (r < Rc && n < Nc) {
                float lg = 10.f * tanhf(acc[i][j] * scale)
                         + mask[((size_t)b * Rc + r) * Nc + n];
                out[((size_t)b * Rc + r) * Nc + n] = lg;
            }
        }
    }
}

// ---------------------------------------------------------------------------
// Kernel 6: row softmax over N=200, in place.
// ---------------------------------------------------------------------------
__global__ __launch_bounds__(64) void softmax_kernel(float* __restrict__ out)
{
    int br = blockIdx.x;
    float* row = out + (size_t)br * Nc;
    int t = threadIdx.x;
    float v[4]; float m = -INFINITY;
    #pragma unroll
    for (int j = 0; j < 4; ++j) {
        int n = t + 64 * j;
        v[j] = (n < Nc) ? row[n] : -INFINITY;
        m = fmaxf(m, v[j]);
    }
    #pragma unroll
    for (int off = 32; off > 0; off >>= 1) m = fmaxf(m, __shfl_xor(m, off));
    float e[4]; float s = 0.f;
    #pragma unroll
    for (int j = 0; j < 4; ++j) {
        e[j] = (v[j] == -INFINITY) ? 0.f : expf(v[j] - m);
        s += e[j];
    }
    #pragma unroll
    for (int off = 32; off > 0; off >>= 1) s += __shfl_xor(s, off);
    float inv = 1.f / s;
    #pragma unroll
    for (int j = 0; j < 4; ++j) {
        int n = t + 64 * j;
        if (n < Nc) row[n] = e[j] * inv;
    }
}

// ---------------------------------------------------------------------------
extern "C" void kernel_launch(void* const* d_in, const int* in_sizes, int n_in,
                              void* d_out, int out_size, void* d_ws, size_t ws_size,
                              hipStream_t stream)
{
    const float* enc  = (const float*)d_in[0];
    const float* dist = (const float*)d_in[1];
    const float* mask = (const float*)d_in[2];
    const int*   cur  = (const int*)d_in[3];
    const float* Wq   = (const float*)d_in[4];
    const float* Wk   = (const float*)d_in[5];
    const float* Wv   = (const float*)d_in[6];
    const float* Wmhc = (const float*)d_in[7];
    const float* bmhc = (const float*)d_in[8];
    const float* W1   = (const float*)d_in[9];
    const float* b1   = (const float*)d_in[10];
    const float* W2   = (const float*)d_in[11];
    const float* b2   = (const float*)d_in[12];
    float* out = (float*)d_out;

    char* ws = (char*)d_ws;
    size_t off = 0;
    auto alloc = [&](size_t bytes) { char* p = ws + off; off += (bytes + 255) & ~(size_t)255; return p; };
    __hip_bfloat16* W1t  = (__hip_bfloat16*)alloc((size_t)640 * 1280 * 2);
    __hip_bfloat16* W2t  = (__hip_bfloat16*)alloc((size_t)128 * 640 * 2);
    __hip_bfloat16* Wqt  = (__hip_bfloat16*)alloc((size_t)128 * 256 * 2);
    __hip_bfloat16* Wmt  = (__hip_bfloat16*)alloc((size_t)128 * 128 * 2);
    __hip_bfloat16* Wkt  = (__hip_bfloat16*)alloc((size_t)128 * 128 * 2);
    __hip_bfloat16* Wvt  = (__hip_bfloat16*)alloc((size_t)128 * 128 * 2);
    __hip_bfloat16* encb = (__hip_bfloat16*)alloc((size_t)Bc * Nc * Dc * 2);
    __hip_bfloat16* bmat = (__hip_bfloat16*)alloc((size_t)BRc * 1280 * 2);
    __hip_bfloat16* h    = (__hip_bfloat16*)alloc((size_t)BRc * 640 * 2);
    __hip_bfloat16* qin  = (__hip_bfloat16*)alloc((size_t)BRc * 256 * 2);
    float* q   = (float*)alloc((size_t)BRc * 128 * 4);
    __hip_bfloat16* kf  = (__hip_bfloat16*)alloc((size_t)Bc * Nc * 128 * 2);
    __hip_bfloat16* vf  = (__hip_bfloat16*)alloc((size_t)Bc * Nc * 128 * 2);
    __hip_bfloat16* att = (__hip_bfloat16*)alloc((size_t)BRc * 128 * 2);
    float* mh  = (float*)alloc((size_t)BRc * 128 * 4);

    convert_transpose_kernel<<<dim3(1280 / 32, 640 / 32), 256, 0, stream>>>(W1, W1t, 1280, 640);
    convert_transpose_kernel<<<dim3(640 / 32, 128 / 32), 256, 0, stream>>>(W2, W2t, 640, 128);
    convert_transpose_kernel<<<dim3(256 / 32, 128 / 32), 256, 0, stream>>>(Wq, Wqt, 256, 128);
    convert_transpose_kernel<<<dim3(128 / 32, 128 / 32), 256, 0, stream>>>(Wmhc, Wmt, 128, 128);
    convert_transpose_kernel<<<dim3(128 / 32, 128 / 32), 256, 0, stream>>>(Wk, Wkt, 128, 128);
    convert_transpose_kernel<<<dim3(128 / 32, 128 / 32), 256, 0, stream>>>(Wv, Wvt, 128, 128);
    f32_to_bf16_kernel<<<(Bc * Nc * Dc) / 1024, 256, 0, stream>>>(enc, encb, Bc * Nc * Dc);

    knn_gather_kernel<<<BRc, 128, 0, stream>>>(enc, dist, mask, cur, bmat, qin);

    // kf = enc @ Wk, vf = enc @ Wv   [6400,128]x[128,128] -> bf16
    mfma_gemm_kernel<false, false, true><<<dim3((Bc * Nc) / 128, 1), 256, 0, stream>>>(
        encb, 128, Wkt, 128, nullptr, kf, 128, 0);
    mfma_gemm_kernel<false, false, true><<<dim3((Bc * Nc) / 128, 1), 256, 0, stream>>>(
        encb, 128, Wvt, 128, nullptr, vf, 128, 0);

    // h = relu(bmat @ W1 + b1)     [6400,1280]x[1280,640] -> bf16
    mfma_gemm_kernel<true, true, true><<<dim3(BRc / 128, 640 / 128), 256, 0, stream>>>(
        bmat, 1280, W1t, 1280, b1, h, 640, 0);
    // qin[:,128:256] = h @ W2 + b2 [6400,640]x[640,128] -> bf16
    mfma_gemm_kernel<false, true, true><<<dim3(BRc / 128, 1), 256, 0, stream>>>(
        h, 640, W2t, 640, b2, qin, 256, 128);
    // q = qin @ Wq                 [6400,256]x[256,128] -> fp32
    mfma_gemm_kernel<false, false, false><<<dim3(BRc / 128, 1), 256, 0, stream>>>(
        qin, 256, Wqt, 256, nullptr, q, 128, 0);

    attn_kernel<<<Bc * Hc, 832, 0, stream>>>(q, kf, vf, mask, att);

    // mh = att @ Wmhc + b_mhc      [6400,128]x[128,128] -> fp32
    mfma_gemm_kernel<false, true, false><<<dim3(BRc / 128, 1), 256, 0, stream>>>(
        att, 128, Wmt, 128, bmhc, mh, 128, 0);

    final_logits_kernel<<<dim3(Bc, 4, 7), 256, 0, stream>>>(mh, enc, mask, out);
    softmax_kernel<<<BRc, 64, 0, stream>>>(out);
}